// Round 5
// baseline (1570.331 us; speedup 1.0000x reference)
//
#include <hip/hip_runtime.h>
#include <stdint.h>

#define RTOT 8192
#define BFWD 16     // rows produced per forward block
#define WFWD 48     // forward warmup steps (generous; tighten after PASS)
#define BBWD 32     // rows per backward block
#define WBWD 48     // backward warmup steps
#define LSTR 36     // LDS row stride in floats

typedef unsigned short u16;
typedef __attribute__((ext_vector_type(4))) float f32x4;
typedef __attribute__((ext_vector_type(8))) unsigned short u16x8;

__device__ __forceinline__ float bf2f(u16 u) { return __uint_as_float(((uint32_t)u) << 16); }
__device__ __forceinline__ float rdlane(float v, int l) {
  return __int_as_float(__builtin_amdgcn_readlane(__float_as_int(v), l));
}

// Dual-dtype input loaders. bf==true: bf16 container; bf==false: fp32 container.
__device__ __forceinline__ void load8(const void* p, size_t off, bool bf, float* o) {
  if (bf) {
    u16x8 v = *(const u16x8*)((const u16*)p + off);
    #pragma unroll
    for (int e = 0; e < 8; ++e) o[e] = bf2f(v[e]);
  } else {
    f32x4 a = *(const f32x4*)((const float*)p + off);
    f32x4 b = *(const f32x4*)((const float*)p + off + 4);
    o[0]=a[0]; o[1]=a[1]; o[2]=a[2]; o[3]=a[3];
    o[4]=b[0]; o[5]=b[1]; o[6]=b[2]; o[7]=b[3];
  }
}
__device__ __forceinline__ float load1(const void* p, size_t off, bool bf) {
  return bf ? bf2f(((const u16*)p)[off]) : ((const float*)p)[off];
}

// ======================= DTYPE DETECTOR =======================
// x_trans_prec (W) is symmetric: bit-equal u16 pairs iff bf16 container.
__global__ void detect_kernel(const void* Wptr, int* flag) {
  if (threadIdx.x == 0) {
    const u16* w = (const u16*)Wptr;
    int ok = 1;
    const int pi[4] = {0, 0, 1, 2};
    const int pj[4] = {1, 2, 2, 3};
    #pragma unroll
    for (int p = 0; p < 4; ++p)
      ok &= (w[pi[p]*32 + pj[p]] == w[pj[p]*32 + pi[p]]) ? 1 : 0;
    *flag = ok;   // 1 = bf16 container, 0 = fp32 container
  }
}

// ============================ FORWARD ============================
// One wave per block; rows [r0, r0+BFWD) after warmup from max(r0-WFWD,0)
// starting at P=W (Ct=0), u=0.
//   S_r = K0 + H_r - Ct^T Ct   (K0 = W + MtPMt)
//   L = chol(S); Linv = L^-1; Ct = Linv*MtP; y = g + u*Ct_prev; u' = Linv*y
// r==0 uses P=x_init_prec exactly; r==R-1 drops MtPMt (m=0).
__global__ __launch_bounds__(64, 1) void fwd_kernel(
    const void* __restrict__ Hg, const void* __restrict__ Gg,
    const void* __restrict__ Mg, const void* __restrict__ Wg,
    const void* __restrict__ Ig, int s0, const int* __restrict__ flag,
    float* __restrict__ gLinv, float* __restrict__ gCt, float* __restrict__ gU)
{
  __shared__ __align__(16) float ldsM[32*LSTR];
  __shared__ __align__(16) float ldsI[32*LSTR];
  __shared__ __align__(16) float ldsMtP[32*LSTR];
  __shared__ __align__(16) float ldsMtPMt[32*LSTR];
  __shared__ __align__(16) float ldsLinv[32*LSTR];
  __shared__ __align__(16) float ldsCt[32*LSTR];
  __shared__ float ldsU[32];
  __shared__ float ldsY[32];

  const bool bf = (*flag != 0);
  const int lane = threadIdx.x & 63;
  const int il = lane & 31;   // lanes 32-63 duplicate lanes 0-31 (benign dup LDS writes)

  float wrow[32], mrow[32];
  #pragma unroll
  for (int c = 0; c < 4; ++c) {
    float wt[8], mt[8], it[8];
    load8(Wg, il*32 + c*8, bf, wt);
    load8(Mg, il*32 + c*8, bf, mt);
    load8(Ig, il*32 + c*8, bf, it);
    #pragma unroll
    for (int e = 0; e < 8; ++e) {
      wrow[c*8+e] = wt[e]; mrow[c*8+e] = mt[e];
      ldsM[il*LSTR + c*8+e] = mt[e];
      ldsI[il*LSTR + c*8+e] = it[e];
      ldsCt[il*LSTR + c*8+e] = 0.0f;
    }
  }
  if (lane < 32) { ldsU[lane] = 0.0f; ldsY[lane] = 0.0f; }
  __syncthreads();

  // MtP[m][il] = sum_t M[m][t] * W[t][il]  (W symmetric)
  #pragma clang loop unroll(disable)
  for (int m = 0; m < 32; ++m) {
    float acc = 0.0f;
    #pragma unroll
    for (int c = 0; c < 8; ++c) {
      f32x4 q = *(const f32x4*)&ldsM[m*LSTR + c*4];
      acc = fmaf(q[0], wrow[c*4+0], acc); acc = fmaf(q[1], wrow[c*4+1], acc);
      acc = fmaf(q[2], wrow[c*4+2], acc); acc = fmaf(q[3], wrow[c*4+3], acc);
    }
    ldsMtP[m*LSTR + il] = acc;
  }
  __syncthreads();
  // MtPMt[m][il] = sum_k MtP[m][k] * M[il][k]
  #pragma clang loop unroll(disable)
  for (int m = 0; m < 32; ++m) {
    float acc = 0.0f;
    #pragma unroll
    for (int c = 0; c < 8; ++c) {
      f32x4 q = *(const f32x4*)&ldsMtP[m*LSTR + c*4];
      acc = fmaf(q[0], mrow[c*4+0], acc); acc = fmaf(q[1], mrow[c*4+1], acc);
      acc = fmaf(q[2], mrow[c*4+2], acc); acc = fmaf(q[3], mrow[c*4+3], acc);
    }
    ldsMtPMt[m*LSTR + il] = acc;
  }
  __syncthreads();

  float mtpcol[32], k0row[32];
  #pragma unroll
  for (int t = 0; t < 32; ++t) mtpcol[t] = ldsMtP[t*LSTR + il];
  #pragma unroll
  for (int k = 0; k < 32; ++k) k0row[k] = wrow[k] + ldsMtPMt[il*LSTR + k];

  const int r0 = s0 + blockIdx.x * BFWD;
  const int rw0 = (r0 >= WFWD) ? (r0 - WFWD) : 0;

  float hcur[32];
  #pragma unroll
  for (int c = 0; c < 4; ++c) load8(Hg, (size_t)rw0*1024 + il*32 + c*8, bf, &hcur[c*8]);
  float gv = load1(Gg, (size_t)rw0*32 + il, bf);

  for (int r = rw0; r < r0 + BFWD; ++r) {
    // prefetch next H,g
    int rn = (r + 1 < RTOT) ? (r + 1) : r;
    float hnext[32];
    #pragma unroll
    for (int c = 0; c < 4; ++c) load8(Hg, (size_t)rn*1024 + il*32 + c*8, bf, &hnext[c*8]);
    float gvn = load1(Gg, (size_t)rn*32 + il, bf);

    // y[il] = g[il] + sum_m u[m] * Ct_prev[m][il]
    float y = gv;
    #pragma clang loop unroll(disable)
    for (int m = 0; m < 32; ++m) y = fmaf(ldsU[m], ldsCt[m*LSTR + il], y);
    ldsY[il] = y;

    // S row il
    float row[32];
    if (r == 0) {
      #pragma unroll
      for (int k = 0; k < 32; ++k) row[k] = hcur[k] + ldsI[il*LSTR+k] + ldsMtPMt[il*LSTR+k];
    } else {
      #pragma unroll
      for (int k = 0; k < 32; ++k) row[k] = hcur[k] + k0row[k];
    }
    #pragma clang loop unroll(disable)
    for (int m = 0; m < 32; ++m) {
      float cm = ldsCt[m*LSTR + il];
      #pragma unroll
      for (int c = 0; c < 8; ++c) {
        f32x4 q = *(const f32x4*)&ldsCt[m*LSTR + c*4];
        row[c*4+0] = fmaf(-cm, q[0], row[c*4+0]);
        row[c*4+1] = fmaf(-cm, q[1], row[c*4+1]);
        row[c*4+2] = fmaf(-cm, q[2], row[c*4+2]);
        row[c*4+3] = fmaf(-cm, q[3], row[c*4+3]);
      }
    }
    if (r == RTOT - 1) {   // m_s = 0 on the last step
      #pragma unroll
      for (int k = 0; k < 32; ++k) row[k] -= ldsMtPMt[il*LSTR+k];
    }

    // Cholesky, row-per-lane, readlane broadcasts
    #pragma unroll
    for (int j = 0; j < 32; ++j) {
      float dj = fmaxf(rdlane(row[j], j), 1e-12f);
      float rs = __builtin_amdgcn_rsqf(dj);
      float cj = row[j] * rs;
      row[j] = cj;
      #pragma unroll
      for (int k = j + 1; k < 32; ++k) {
        float ck = rdlane(row[j], k);
        row[k] = fmaf(-cj, ck, row[k]);
      }
    }

    // Linv column il
    float linv[32];
    #pragma unroll
    for (int i = 0; i < 32; ++i) {
      float acc = (il == i) ? 1.0f : 0.0f;
      #pragma unroll
      for (int m = 0; m < i; ++m) {
        float Lim = rdlane(row[m], i);
        acc = fmaf(-Lim, linv[m], acc);
      }
      float Lii = rdlane(row[i], i);
      linv[i] = acc * __builtin_amdgcn_rcpf(Lii);
    }

    #pragma unroll
    for (int i = 0; i < 32; ++i) ldsLinv[i*LSTR + il] = linv[i];
    __syncthreads();

    // u_new[il] = sum_m Linv[il][m] * y[m]
    float un = 0.0f;
    #pragma clang loop unroll(disable)
    for (int m = 0; m < 32; ++m) un = fmaf(ldsLinv[il*LSTR + m], ldsY[m], un);
    ldsU[il] = un;

    // Ct_new[m][il] = sum_t Linv[m][t] * MtP[t][il]
    #pragma clang loop unroll(disable)
    for (int m = 0; m < 32; ++m) {
      float a = 0.0f;
      #pragma unroll
      for (int c = 0; c < 8; ++c) {
        f32x4 q = *(const f32x4*)&ldsLinv[m*LSTR + c*4];
        a = fmaf(q[0], mtpcol[c*4+0], a);
        a = fmaf(q[1], mtpcol[c*4+1], a);
        a = fmaf(q[2], mtpcol[c*4+2], a);
        a = fmaf(q[3], mtpcol[c*4+3], a);
      }
      ldsCt[m*LSTR + il] = a;
    }
    __syncthreads();

    if (r >= r0) {
      size_t ro = (size_t)(r - s0);
      #pragma unroll
      for (int c = 0; c < 4; ++c) {
        int f = lane*16 + c*4;
        int mm = f >> 5, kk = f & 31;
        *(f32x4*)&gLinv[ro*1024 + f] = *(const f32x4*)&ldsLinv[mm*LSTR + kk];
        *(f32x4*)&gCt [ro*1024 + f] = *(const f32x4*)&ldsCt [mm*LSTR + kk];
      }
      if (lane < 32) gU[ro*32 + il] = un;
    }

    #pragma unroll
    for (int c = 0; c < 4; ++c) {
      #pragma unroll
      for (int e = 0; e < 8; ++e) hcur[c*8+e] = hnext[c*8+e];
    }
    gv = gvn;
  }
}

// ============================ BACKWARD ============================
//   X[s][k]   = G[s][k] + sum_m vw[s][m] * B1[k][m]   (B1 = Ct row-major)
//   vw'[s][j] = sum_k X[s][k] * B2[k][j]              (B2 = Linv row-major)
//   out[r][j][:] = vw'[0][:] + vw'[1+j][:]   (fp32 output)
#define MM1(SVAL, GARR)                                                   \
  { int s_ = (SVAL);                                                      \
    float vr[32];                                                         \
    _Pragma("unroll")                                                     \
    for (int c = 0; c < 8; ++c) {                                         \
      f32x4 q = *(const f32x4*)&vw[s_*LSTR + c*4];                        \
      vr[c*4+0]=q[0]; vr[c*4+1]=q[1]; vr[c*4+2]=q[2]; vr[c*4+3]=q[3];     \
    }                                                                     \
    float xr[8];                                                          \
    _Pragma("unroll")                                                     \
    for (int e = 0; e < 8; ++e) {                                         \
      int k_ = oct*8 + e;                                                 \
      float acc = GARR[e];                                                \
      _Pragma("unroll")                                                   \
      for (int c = 0; c < 8; ++c) {                                       \
        f32x4 b = *(const f32x4*)&B1[k_*LSTR + c*4];                      \
        acc = fmaf(vr[c*4+0], b[0], acc);                                 \
        acc = fmaf(vr[c*4+1], b[1], acc);                                 \
        acc = fmaf(vr[c*4+2], b[2], acc);                                 \
        acc = fmaf(vr[c*4+3], b[3], acc);                                 \
      }                                                                   \
      xr[e] = acc;                                                        \
    }                                                                     \
    f32x4 xa = { xr[0], xr[1], xr[2], xr[3] };                            \
    f32x4 xb = { xr[4], xr[5], xr[6], xr[7] };                            \
    *(f32x4*)&Xs[s_*LSTR + oct*8] = xa;                                   \
    *(f32x4*)&Xs[s_*LSTR + oct*8 + 4] = xb;                               \
  }

#define MM2(SVAL)                                                         \
  { int s_ = (SVAL);                                                      \
    float xrr[32];                                                        \
    _Pragma("unroll")                                                     \
    for (int c = 0; c < 8; ++c) {                                         \
      f32x4 q = *(const f32x4*)&Xs[s_*LSTR + c*4];                        \
      xrr[c*4+0]=q[0]; xrr[c*4+1]=q[1]; xrr[c*4+2]=q[2]; xrr[c*4+3]=q[3]; \
    }                                                                     \
    float a0=0,a1=0,a2=0,a3=0,a4=0,a5=0,a6=0,a7=0;                        \
    _Pragma("unroll")                                                     \
    for (int k_ = 0; k_ < 32; ++k_) {                                     \
      f32x4 b = *(const f32x4*)&B2[k_*LSTR + oct*8];                      \
      f32x4 b2 = *(const f32x4*)&B2[k_*LSTR + oct*8 + 4];                 \
      float xk = xrr[k_];                                                 \
      a0 = fmaf(xk, b[0], a0);  a1 = fmaf(xk, b[1], a1);                  \
      a2 = fmaf(xk, b[2], a2);  a3 = fmaf(xk, b[3], a3);                  \
      a4 = fmaf(xk, b2[0], a4); a5 = fmaf(xk, b2[1], a5);                 \
      a6 = fmaf(xk, b2[2], a6); a7 = fmaf(xk, b2[3], a7);                 \
    }                                                                     \
    f32x4 va = { a0, a1, a2, a3 };                                        \
    f32x4 vb = { a4, a5, a6, a7 };                                        \
    *(f32x4*)&vw[s_*LSTR + oct*8] = va;                                   \
    *(f32x4*)&vw[s_*LSTR + oct*8 + 4] = vb;                               \
  }

__global__ __launch_bounds__(256, 1) void bwd_kernel(
    const void* __restrict__ Eg,
    const float* __restrict__ gLinv, const float* __restrict__ gCt,
    const float* __restrict__ gU, float* __restrict__ outg, int s0,
    const int* __restrict__ flag)
{
  __shared__ __align__(16) float vw[65*LSTR];
  __shared__ __align__(16) float Xs[65*LSTR];
  __shared__ __align__(16) float B1[32*LSTR];
  __shared__ __align__(16) float B2[32*LSTR];

  const bool bf = (*flag != 0);
  const int t = threadIdx.x;
  const int ss = t >> 2;
  const int oct = t & 3;

  const int r0 = s0 + blockIdx.x * BBWD;
  int re = r0 + BBWD - 1 + WBWD; if (re > RTOT-1) re = RTOT-1;

  for (int i = t; i < 65*LSTR; i += 256) vw[i] = 0.0f;

  // prefetch for r = re
  size_t reo = (size_t)(re - s0);
  f32x4 pB1 = *(const f32x4*)&gCt[reo*1024 + t*4];
  f32x4 pB2 = *(const f32x4*)&gLinv[reo*1024 + t*4];
  float pg0[8], pg1[8];
  if (ss == 0) {
    f32x4 a = *(const f32x4*)&gU[reo*32 + oct*8];
    f32x4 b = *(const f32x4*)&gU[reo*32 + oct*8 + 4];
    pg0[0]=a[0];pg0[1]=a[1];pg0[2]=a[2];pg0[3]=a[3];
    pg0[4]=b[0];pg0[5]=b[1];pg0[6]=b[2];pg0[7]=b[3];
  } else {
    load8(Eg, ((size_t)re*64 + (ss-1))*32 + oct*8, bf, pg0);
  }
  load8(Eg, ((size_t)re*64 + 63)*32 + oct*8, bf, pg1);

  float gc0[8], gc1[8];

  for (int r = re; r >= r0; --r) {
    { // stage prefetched B1/B2/G
      int mm = t >> 3, kk = (t & 7) * 4;
      *(f32x4*)&B1[mm*LSTR + kk] = pB1;
      *(f32x4*)&B2[mm*LSTR + kk] = pB2;
      #pragma unroll
      for (int e = 0; e < 8; ++e) { gc0[e] = pg0[e]; gc1[e] = pg1[e]; }
    }
    __syncthreads();

    if (r > r0) {  // issue prefetch for r-1
      size_t r1o = (size_t)(r - 1 - s0);
      int r1 = r - 1;
      pB1 = *(const f32x4*)&gCt[r1o*1024 + t*4];
      pB2 = *(const f32x4*)&gLinv[r1o*1024 + t*4];
      if (ss == 0) {
        f32x4 a = *(const f32x4*)&gU[r1o*32 + oct*8];
        f32x4 b = *(const f32x4*)&gU[r1o*32 + oct*8 + 4];
        pg0[0]=a[0];pg0[1]=a[1];pg0[2]=a[2];pg0[3]=a[3];
        pg0[4]=b[0];pg0[5]=b[1];pg0[6]=b[2];pg0[7]=b[3];
      } else {
        load8(Eg, ((size_t)r1*64 + (ss-1))*32 + oct*8, bf, pg0);
      }
      load8(Eg, ((size_t)r1*64 + 63)*32 + oct*8, bf, pg1);
    }

    MM1(ss, gc0)
    if (t < 4) MM1(64, gc1)
    __syncthreads();

    MM2(ss)
    if (t < 4) MM2(64)
    __syncthreads();

    if (r < r0 + BBWD) {
      int j = t >> 2, c0 = (t & 3) * 8;
      f32x4 a0 = *(const f32x4*)&vw[(1+j)*LSTR + c0];
      f32x4 a1 = *(const f32x4*)&vw[(1+j)*LSTR + c0 + 4];
      f32x4 b0 = *(const f32x4*)&vw[c0];
      f32x4 b1 = *(const f32x4*)&vw[c0 + 4];
      f32x4 o0, o1;
      o0[0]=a0[0]+b0[0]; o0[1]=a0[1]+b0[1]; o0[2]=a0[2]+b0[2]; o0[3]=a0[3]+b0[3];
      o1[0]=a1[0]+b1[0]; o1[1]=a1[1]+b1[1]; o1[2]=a1[2]+b1[2]; o1[3]=a1[3]+b1[3];
      float* dst = outg + ((size_t)r*64 + j)*32 + c0;
      *(f32x4*)dst = o0;
      *(f32x4*)(dst + 4) = o1;
    }
  }
}

extern "C" void kernel_launch(void* const* d_in, const int* in_sizes, int n_in,
                              void* d_out, int out_size, void* d_ws, size_t ws_size,
                              hipStream_t stream) {
  (void)in_sizes; (void)n_in; (void)out_size;
  const void* H = d_in[0];   // x_hessian_diags [R,32,32] fp32
  const void* G = d_in[1];   // x_grads         [R,1,32]  fp32
  const void* M = d_in[2];   // x_trans_mat     [32,32]   fp32
  const void* W = d_in[3];   // x_trans_prec    [32,32]   fp32
  const void* I = d_in[4];   // x_init_prec     [32,32]   fp32
  const void* E = d_in[5];   // epsx            [R,64,32] fp32
  float* out = (float*)d_out;  // [R,64,32] fp32 (reference output dtype)

  int* flag = (int*)d_ws;                         // dtype flag (first 256 B reserved)
  float* ws0 = (float*)((char*)d_ws + 256);
  size_t avail = (ws_size > 256) ? (ws_size - 256) : 0;

  // Segment R so fp32 Linv/Ct/U (8320 B/row incl. +WBWD extension rows) fit.
  int nseg = 64;
  for (int cand = 1; cand <= 64; cand <<= 1) {
    size_t nrext = (size_t)(RTOT / cand) + WBWD;
    if (nrext * 8320 <= avail) { nseg = cand; break; }
  }
  const int segrows = RTOT / nseg;
  const size_t nrext_max = (size_t)segrows + WBWD;

  float* gLinv = ws0;
  float* gCt  = ws0 + nrext_max * 1024;
  float* gU   = ws0 + nrext_max * 2048;

  detect_kernel<<<1, 64, 0, stream>>>(W, flag);

  for (int s = 0; s < nseg; ++s) {
    int s0 = s * segrows;
    int s1ext = s0 + segrows + WBWD; if (s1ext > RTOT) s1ext = RTOT;
    fwd_kernel<<<(s1ext - s0) / BFWD, 64, 0, stream>>>(H, G, M, W, I, s0, flag, gLinv, gCt, gU);
    bwd_kernel<<<segrows / BBWD, 256, 0, stream>>>(E, gLinv, gCt, gU, out, s0, flag);
  }
}

// Round 6
// 1293.111 us; speedup vs baseline: 1.2144x; 1.2144x over previous
//
#include <hip/hip_runtime.h>
#include <stdint.h>

#define RTOT 8192
#define BFWD 8      // rows produced per forward block
#define WFWD 32     // forward warmup steps
#define BBWD 32     // rows per backward block
#define WBWD 32     // backward warmup steps
#define LSTR 36     // LDS row stride in floats

typedef unsigned short u16;
typedef __attribute__((ext_vector_type(4))) float f32x4;
typedef __attribute__((ext_vector_type(8))) unsigned short u16x8;

__device__ __forceinline__ float bf2f(u16 u) { return __uint_as_float(((uint32_t)u) << 16); }
__device__ __forceinline__ float rdlane(float v, int l) {
  return __int_as_float(__builtin_amdgcn_readlane(__float_as_int(v), l));
}

// Dual-dtype input loaders. bf==true: bf16 container; bf==false: fp32 container.
__device__ __forceinline__ void load8(const void* p, size_t off, bool bf, float* o) {
  if (bf) {
    u16x8 v = *(const u16x8*)((const u16*)p + off);
    #pragma unroll
    for (int e = 0; e < 8; ++e) o[e] = bf2f(v[e]);
  } else {
    f32x4 a = *(const f32x4*)((const float*)p + off);
    f32x4 b = *(const f32x4*)((const float*)p + off + 4);
    o[0]=a[0]; o[1]=a[1]; o[2]=a[2]; o[3]=a[3];
    o[4]=b[0]; o[5]=b[1]; o[6]=b[2]; o[7]=b[3];
  }
}
__device__ __forceinline__ float load1(const void* p, size_t off, bool bf) {
  return bf ? bf2f(((const u16*)p)[off]) : ((const float*)p)[off];
}

// ======================= DTYPE DETECTOR =======================
__global__ void detect_kernel(const void* Wptr, int* flag) {
  if (threadIdx.x == 0) {
    const u16* w = (const u16*)Wptr;
    int ok = 1;
    const int pi[4] = {0, 0, 1, 2};
    const int pj[4] = {1, 2, 2, 3};
    #pragma unroll
    for (int p = 0; p < 4; ++p)
      ok &= (w[pi[p]*32 + pj[p]] == w[pj[p]*32 + pi[p]]) ? 1 : 0;
    *flag = ok;   // 1 = bf16 container, 0 = fp32 container
  }
}

// ============================ FORWARD ============================
// One wave per block; rows [r0, r0+BFWD) after warmup from max(r0-WFWD,0)
// starting at P=W (Ct=0), u=0.
//   S_r = K0 + H_r - Ct^T Ct   (K0 = W + MtPMt)
//   L = chol(S); Linv = L^-1; Ct = Linv*MtP; y = g + u*Ct_prev; u' = Linv*y
// r==0 uses P=x_init_prec exactly; r==R-1 drops MtPMt (m=0).
__global__ __launch_bounds__(64, 1) void fwd_kernel(
    const void* __restrict__ Hg, const void* __restrict__ Gg,
    const void* __restrict__ Mg, const void* __restrict__ Wg,
    const void* __restrict__ Ig, int s0, const int* __restrict__ flag,
    float* __restrict__ gLinv, float* __restrict__ gCt, float* __restrict__ gU)
{
  __shared__ __align__(16) float ldsM[32*LSTR];
  __shared__ __align__(16) float ldsI[32*LSTR];
  __shared__ __align__(16) float ldsMtP[32*LSTR];
  __shared__ __align__(16) float ldsMtPMt[32*LSTR];
  __shared__ __align__(16) float ldsLinv[32*LSTR];
  __shared__ __align__(16) float ldsCt[32*LSTR];
  __shared__ float ldsU[32];
  __shared__ float ldsY[32];

  const bool bf = (*flag != 0);
  const int lane = threadIdx.x & 63;
  const int il = lane & 31;   // lanes 32-63 duplicate lanes 0-31 (benign dup LDS writes)

  float wrow[32], mrow[32];
  #pragma unroll
  for (int c = 0; c < 4; ++c) {
    float wt[8], mt[8], it[8];
    load8(Wg, il*32 + c*8, bf, wt);
    load8(Mg, il*32 + c*8, bf, mt);
    load8(Ig, il*32 + c*8, bf, it);
    #pragma unroll
    for (int e = 0; e < 8; ++e) {
      wrow[c*8+e] = wt[e]; mrow[c*8+e] = mt[e];
      ldsM[il*LSTR + c*8+e] = mt[e];
      ldsI[il*LSTR + c*8+e] = it[e];
      ldsCt[il*LSTR + c*8+e] = 0.0f;
    }
  }
  if (lane < 32) { ldsU[lane] = 0.0f; ldsY[lane] = 0.0f; }
  __syncthreads();

  // MtP[m][il] = sum_t M[m][t] * W[t][il]  (W symmetric)
  #pragma unroll 4
  for (int m = 0; m < 32; ++m) {
    float acc = 0.0f;
    #pragma unroll
    for (int c = 0; c < 8; ++c) {
      f32x4 q = *(const f32x4*)&ldsM[m*LSTR + c*4];
      acc = fmaf(q[0], wrow[c*4+0], acc); acc = fmaf(q[1], wrow[c*4+1], acc);
      acc = fmaf(q[2], wrow[c*4+2], acc); acc = fmaf(q[3], wrow[c*4+3], acc);
    }
    ldsMtP[m*LSTR + il] = acc;
  }
  __syncthreads();
  // MtPMt[m][il] = sum_k MtP[m][k] * M[il][k]
  #pragma unroll 4
  for (int m = 0; m < 32; ++m) {
    float acc = 0.0f;
    #pragma unroll
    for (int c = 0; c < 8; ++c) {
      f32x4 q = *(const f32x4*)&ldsMtP[m*LSTR + c*4];
      acc = fmaf(q[0], mrow[c*4+0], acc); acc = fmaf(q[1], mrow[c*4+1], acc);
      acc = fmaf(q[2], mrow[c*4+2], acc); acc = fmaf(q[3], mrow[c*4+3], acc);
    }
    ldsMtPMt[m*LSTR + il] = acc;
  }
  __syncthreads();

  float mtpcol[32], k0row[32];
  #pragma unroll
  for (int t = 0; t < 32; ++t) mtpcol[t] = ldsMtP[t*LSTR + il];
  #pragma unroll
  for (int k = 0; k < 32; ++k) k0row[k] = wrow[k] + ldsMtPMt[il*LSTR + k];

  const int r0 = s0 + blockIdx.x * BFWD;
  const int rw0 = (r0 >= WFWD) ? (r0 - WFWD) : 0;

  float hcur[32];
  #pragma unroll
  for (int c = 0; c < 4; ++c) load8(Hg, (size_t)rw0*1024 + il*32 + c*8, bf, &hcur[c*8]);
  float gv = load1(Gg, (size_t)rw0*32 + il, bf);

  for (int r = rw0; r < r0 + BFWD; ++r) {
    // prefetch next H,g
    int rn = (r + 1 < RTOT) ? (r + 1) : r;
    float hnext[32];
    #pragma unroll
    for (int c = 0; c < 4; ++c) load8(Hg, (size_t)rn*1024 + il*32 + c*8, bf, &hnext[c*8]);
    float gvn = load1(Gg, (size_t)rn*32 + il, bf);

    // y[il] = g[il] + sum_m u[m] * Ct_prev[m][il]
    float y = gv;
    #pragma unroll 8
    for (int m = 0; m < 32; ++m) y = fmaf(ldsU[m], ldsCt[m*LSTR + il], y);
    ldsY[il] = y;

    // S row il
    float row[32];
    if (r == 0) {
      #pragma unroll
      for (int k = 0; k < 32; ++k) row[k] = hcur[k] + ldsI[il*LSTR+k] + ldsMtPMt[il*LSTR+k];
    } else {
      #pragma unroll
      for (int k = 0; k < 32; ++k) row[k] = hcur[k] + k0row[k];
    }
    #pragma unroll 4
    for (int m = 0; m < 32; ++m) {
      float cm = ldsCt[m*LSTR + il];
      #pragma unroll
      for (int c = 0; c < 8; ++c) {
        f32x4 q = *(const f32x4*)&ldsCt[m*LSTR + c*4];
        row[c*4+0] = fmaf(-cm, q[0], row[c*4+0]);
        row[c*4+1] = fmaf(-cm, q[1], row[c*4+1]);
        row[c*4+2] = fmaf(-cm, q[2], row[c*4+2]);
        row[c*4+3] = fmaf(-cm, q[3], row[c*4+3]);
      }
    }
    if (r == RTOT - 1) {   // m_s = 0 on the last step
      #pragma unroll
      for (int k = 0; k < 32; ++k) row[k] -= ldsMtPMt[il*LSTR+k];
    }

    // Cholesky, row-per-lane, readlane broadcasts
    #pragma unroll
    for (int j = 0; j < 32; ++j) {
      float dj = fmaxf(rdlane(row[j], j), 1e-12f);
      float rs = __builtin_amdgcn_rsqf(dj);
      float cj = row[j] * rs;
      row[j] = cj;
      #pragma unroll
      for (int k = j + 1; k < 32; ++k) {
        float ck = rdlane(row[j], k);
        row[k] = fmaf(-cj, ck, row[k]);
      }
    }

    // Linv column il
    float linv[32];
    #pragma unroll
    for (int i = 0; i < 32; ++i) {
      float acc = (il == i) ? 1.0f : 0.0f;
      #pragma unroll
      for (int m = 0; m < i; ++m) {
        float Lim = rdlane(row[m], i);
        acc = fmaf(-Lim, linv[m], acc);
      }
      float Lii = rdlane(row[i], i);
      linv[i] = acc * __builtin_amdgcn_rcpf(Lii);
    }

    #pragma unroll
    for (int i = 0; i < 32; ++i) ldsLinv[i*LSTR + il] = linv[i];
    __syncthreads();

    // u_new[il] = sum_m Linv[il][m] * y[m]
    float un = 0.0f;
    #pragma unroll 8
    for (int m = 0; m < 32; ++m) un = fmaf(ldsLinv[il*LSTR + m], ldsY[m], un);
    ldsU[il] = un;

    // Ct_new[m][il] = sum_t Linv[m][t] * MtP[t][il]
    #pragma unroll 4
    for (int m = 0; m < 32; ++m) {
      float a = 0.0f;
      #pragma unroll
      for (int c = 0; c < 8; ++c) {
        f32x4 q = *(const f32x4*)&ldsLinv[m*LSTR + c*4];
        a = fmaf(q[0], mtpcol[c*4+0], a);
        a = fmaf(q[1], mtpcol[c*4+1], a);
        a = fmaf(q[2], mtpcol[c*4+2], a);
        a = fmaf(q[3], mtpcol[c*4+3], a);
      }
      ldsCt[m*LSTR + il] = a;
    }
    __syncthreads();

    if (r >= r0) {
      size_t ro = (size_t)(r - s0);
      #pragma unroll
      for (int c = 0; c < 4; ++c) {
        int f = lane*16 + c*4;
        int mm = f >> 5, kk = f & 31;
        *(f32x4*)&gLinv[ro*1024 + f] = *(const f32x4*)&ldsLinv[mm*LSTR + kk];
        *(f32x4*)&gCt [ro*1024 + f] = *(const f32x4*)&ldsCt [mm*LSTR + kk];
      }
      if (lane < 32) gU[ro*32 + il] = un;
    }

    #pragma unroll
    for (int c = 0; c < 4; ++c) {
      #pragma unroll
      for (int e = 0; e < 8; ++e) hcur[c*8+e] = hnext[c*8+e];
    }
    gv = gvn;
  }
}

// ============================ BACKWARD ============================
//   X[s][k]   = G[s][k] + sum_m vw[s][m] * B1[k][m]   (B1 = Ct row-major)
//   vw'[s][j] = sum_k X[s][k] * B2[k][j]              (B2 = Linv row-major)
//   out[r][j][:] = vw'[0][:] + vw'[1+j][:]   (fp32 output)
#define MM1(SVAL, GARR)                                                   \
  { int s_ = (SVAL);                                                      \
    float vr[32];                                                         \
    _Pragma("unroll")                                                     \
    for (int c = 0; c < 8; ++c) {                                         \
      f32x4 q = *(const f32x4*)&vw[s_*LSTR + c*4];                        \
      vr[c*4+0]=q[0]; vr[c*4+1]=q[1]; vr[c*4+2]=q[2]; vr[c*4+3]=q[3];     \
    }                                                                     \
    float xr[8];                                                          \
    _Pragma("unroll")                                                     \
    for (int e = 0; e < 8; ++e) {                                         \
      int k_ = oct*8 + e;                                                 \
      float acc = GARR[e];                                                \
      _Pragma("unroll")                                                   \
      for (int c = 0; c < 8; ++c) {                                       \
        f32x4 b = *(const f32x4*)&B1[k_*LSTR + c*4];                      \
        acc = fmaf(vr[c*4+0], b[0], acc);                                 \
        acc = fmaf(vr[c*4+1], b[1], acc);                                 \
        acc = fmaf(vr[c*4+2], b[2], acc);                                 \
        acc = fmaf(vr[c*4+3], b[3], acc);                                 \
      }                                                                   \
      xr[e] = acc;                                                        \
    }                                                                     \
    f32x4 xa = { xr[0], xr[1], xr[2], xr[3] };                            \
    f32x4 xb = { xr[4], xr[5], xr[6], xr[7] };                            \
    *(f32x4*)&Xs[s_*LSTR + oct*8] = xa;                                   \
    *(f32x4*)&Xs[s_*LSTR + oct*8 + 4] = xb;                               \
  }

#define MM2(SVAL)                                                         \
  { int s_ = (SVAL);                                                      \
    float xrr[32];                                                        \
    _Pragma("unroll")                                                     \
    for (int c = 0; c < 8; ++c) {                                         \
      f32x4 q = *(const f32x4*)&Xs[s_*LSTR + c*4];                        \
      xrr[c*4+0]=q[0]; xrr[c*4+1]=q[1]; xrr[c*4+2]=q[2]; xrr[c*4+3]=q[3]; \
    }                                                                     \
    float a0=0,a1=0,a2=0,a3=0,a4=0,a5=0,a6=0,a7=0;                        \
    _Pragma("unroll")                                                     \
    for (int k_ = 0; k_ < 32; ++k_) {                                     \
      f32x4 b = *(const f32x4*)&B2[k_*LSTR + oct*8];                      \
      f32x4 b2 = *(const f32x4*)&B2[k_*LSTR + oct*8 + 4];                 \
      float xk = xrr[k_];                                                 \
      a0 = fmaf(xk, b[0], a0);  a1 = fmaf(xk, b[1], a1);                  \
      a2 = fmaf(xk, b[2], a2);  a3 = fmaf(xk, b[3], a3);                  \
      a4 = fmaf(xk, b2[0], a4); a5 = fmaf(xk, b2[1], a5);                 \
      a6 = fmaf(xk, b2[2], a6); a7 = fmaf(xk, b2[3], a7);                 \
    }                                                                     \
    f32x4 va = { a0, a1, a2, a3 };                                        \
    f32x4 vb = { a4, a5, a6, a7 };                                        \
    *(f32x4*)&vw[s_*LSTR + oct*8] = va;                                   \
    *(f32x4*)&vw[s_*LSTR + oct*8 + 4] = vb;                               \
  }

__global__ __launch_bounds__(256, 1) void bwd_kernel(
    const void* __restrict__ Eg,
    const float* __restrict__ gLinv, const float* __restrict__ gCt,
    const float* __restrict__ gU, float* __restrict__ outg, int s0,
    const int* __restrict__ flag)
{
  __shared__ __align__(16) float vw[65*LSTR];
  __shared__ __align__(16) float Xs[65*LSTR];
  __shared__ __align__(16) float B1[32*LSTR];
  __shared__ __align__(16) float B2[32*LSTR];

  const bool bf = (*flag != 0);
  const int t = threadIdx.x;
  const int ss = t >> 2;
  const int oct = t & 3;

  const int r0 = s0 + blockIdx.x * BBWD;
  int re = r0 + BBWD - 1 + WBWD; if (re > RTOT-1) re = RTOT-1;

  for (int i = t; i < 65*LSTR; i += 256) vw[i] = 0.0f;

  // prefetch for r = re
  size_t reo = (size_t)(re - s0);
  f32x4 pB1 = *(const f32x4*)&gCt[reo*1024 + t*4];
  f32x4 pB2 = *(const f32x4*)&gLinv[reo*1024 + t*4];
  float pg0[8], pg1[8];
  if (ss == 0) {
    f32x4 a = *(const f32x4*)&gU[reo*32 + oct*8];
    f32x4 b = *(const f32x4*)&gU[reo*32 + oct*8 + 4];
    pg0[0]=a[0];pg0[1]=a[1];pg0[2]=a[2];pg0[3]=a[3];
    pg0[4]=b[0];pg0[5]=b[1];pg0[6]=b[2];pg0[7]=b[3];
  } else {
    load8(Eg, ((size_t)re*64 + (ss-1))*32 + oct*8, bf, pg0);
  }
  load8(Eg, ((size_t)re*64 + 63)*32 + oct*8, bf, pg1);

  float gc0[8], gc1[8];

  for (int r = re; r >= r0; --r) {
    { // stage prefetched B1/B2/G
      int mm = t >> 3, kk = (t & 7) * 4;
      *(f32x4*)&B1[mm*LSTR + kk] = pB1;
      *(f32x4*)&B2[mm*LSTR + kk] = pB2;
      #pragma unroll
      for (int e = 0; e < 8; ++e) { gc0[e] = pg0[e]; gc1[e] = pg1[e]; }
    }
    __syncthreads();

    if (r > r0) {  // issue prefetch for r-1
      size_t r1o = (size_t)(r - 1 - s0);
      int r1 = r - 1;
      pB1 = *(const f32x4*)&gCt[r1o*1024 + t*4];
      pB2 = *(const f32x4*)&gLinv[r1o*1024 + t*4];
      if (ss == 0) {
        f32x4 a = *(const f32x4*)&gU[r1o*32 + oct*8];
        f32x4 b = *(const f32x4*)&gU[r1o*32 + oct*8 + 4];
        pg0[0]=a[0];pg0[1]=a[1];pg0[2]=a[2];pg0[3]=a[3];
        pg0[4]=b[0];pg0[5]=b[1];pg0[6]=b[2];pg0[7]=b[3];
      } else {
        load8(Eg, ((size_t)r1*64 + (ss-1))*32 + oct*8, bf, pg0);
      }
      load8(Eg, ((size_t)r1*64 + 63)*32 + oct*8, bf, pg1);
    }

    MM1(ss, gc0)
    if (t < 4) MM1(64, gc1)
    __syncthreads();

    MM2(ss)
    if (t < 4) MM2(64)
    __syncthreads();

    if (r < r0 + BBWD) {
      int j = t >> 2, c0 = (t & 3) * 8;
      f32x4 a0 = *(const f32x4*)&vw[(1+j)*LSTR + c0];
      f32x4 a1 = *(const f32x4*)&vw[(1+j)*LSTR + c0 + 4];
      f32x4 b0 = *(const f32x4*)&vw[c0];
      f32x4 b1 = *(const f32x4*)&vw[c0 + 4];
      f32x4 o0, o1;
      o0[0]=a0[0]+b0[0]; o0[1]=a0[1]+b0[1]; o0[2]=a0[2]+b0[2]; o0[3]=a0[3]+b0[3];
      o1[0]=a1[0]+b1[0]; o1[1]=a1[1]+b1[1]; o1[2]=a1[2]+b1[2]; o1[3]=a1[3]+b1[3];
      float* dst = outg + ((size_t)r*64 + j)*32 + c0;
      *(f32x4*)dst = o0;
      *(f32x4*)(dst + 4) = o1;
    }
  }
}

extern "C" void kernel_launch(void* const* d_in, const int* in_sizes, int n_in,
                              void* d_out, int out_size, void* d_ws, size_t ws_size,
                              hipStream_t stream) {
  (void)in_sizes; (void)n_in; (void)out_size;
  const void* H = d_in[0];   // x_hessian_diags [R,32,32] fp32
  const void* G = d_in[1];   // x_grads         [R,1,32]  fp32
  const void* M = d_in[2];   // x_trans_mat     [32,32]   fp32
  const void* W = d_in[3];   // x_trans_prec    [32,32]   fp32
  const void* I = d_in[4];   // x_init_prec     [32,32]   fp32
  const void* E = d_in[5];   // epsx            [R,64,32] fp32
  float* out = (float*)d_out;  // [R,64,32] fp32 (reference output dtype)

  int* flag = (int*)d_ws;                         // dtype flag (first 256 B reserved)
  float* ws0 = (float*)((char*)d_ws + 256);
  size_t avail = (ws_size > 256) ? (ws_size - 256) : 0;

  // Segment R so fp32 Linv/Ct/U (8320 B/row incl. +WBWD extension rows) fit.
  int nseg = 64;
  for (int cand = 1; cand <= 64; cand <<= 1) {
    size_t nrext = (size_t)(RTOT / cand) + WBWD;
    if (nrext * 8320 <= avail) { nseg = cand; break; }
  }
  const int segrows = RTOT / nseg;
  const size_t nrext_max = (size_t)segrows + WBWD;

  float* gLinv = ws0;
  float* gCt  = ws0 + nrext_max * 1024;
  float* gU   = ws0 + nrext_max * 2048;

  detect_kernel<<<1, 64, 0, stream>>>(W, flag);

  for (int s = 0; s < nseg; ++s) {
    int s0 = s * segrows;
    int s1ext = s0 + segrows + WBWD; if (s1ext > RTOT) s1ext = RTOT;
    fwd_kernel<<<(s1ext - s0) / BFWD, 64, 0, stream>>>(H, G, M, W, I, s0, flag, gLinv, gCt, gU);
    bwd_kernel<<<segrows / BBWD, 256, 0, stream>>>(E, gLinv, gCt, gU, out, s0, flag);
  }
}